// Round 11
// baseline (71.178 us; speedup 1.0000x reference)
//
#include <hip/hip_runtime.h>
#include <stdint.h>

#define BB 16
#define TT 4096
#define DDIM 512
#define KK 128
#define TCB 128            // t-rows per chunk
#define NCB (TT / TCB)     // 32 chunks
#define PI_F 3.14159265358979323846f

typedef unsigned short u16;
typedef __attribute__((ext_vector_type(8))) short short8;
typedef __attribute__((ext_vector_type(4))) float f32x4;

__device__ __forceinline__ uint32_t cvt_bf16_rn(float f) {
  uint32_t u = __float_as_uint(f);
  return (u + 0x7FFFu + ((u >> 16) & 1u)) >> 16;
}
__device__ __forceinline__ uint32_t pack2(float a, float b) {
  return cvt_bf16_rn(a) | (cvt_bf16_rn(b) << 16);
}
__device__ __forceinline__ uint4 pack8(const float4 f0, const float4 f1) {
  uint4 r;
  r.x = pack2(f0.x, f0.y);
  r.y = pack2(f0.z, f0.w);
  r.z = pack2(f1.x, f1.y);
  r.w = pack2(f1.z, f1.w);
  return r;
}
__device__ __forceinline__ void gload_lds16(const void* g, void* l) {
  __builtin_amdgcn_global_load_lds(
      (const __attribute__((address_space(1))) void*)g,
      (__attribute__((address_space(3))) void*)l, 16, 0, 0);
}

// ---------------- kernel 0: fused prep (wpack | ct | params) ----------------
__global__ __launch_bounds__(256) void k_prep(
    const float* __restrict__ W, const float* __restrict__ u_sn,
    const float* __restrict__ s_real_raw, const float* __restrict__ s_imag,
    const float* __restrict__ bias, const float* __restrict__ b_log,
    const float* __restrict__ dt,
    float* __restrict__ params, u16* __restrict__ Wp, float* __restrict__ ct) {
  int gb = blockIdx.x;
  int tid = threadIdx.x;
  if (gb < 64) {
    int idx = gb * 256 + tid;
    int k = idx >> 7;
    int d = (idx & 127) * 4;
    float4 v = *(const float4*)&W[(size_t)k * DDIM + d];
    int tile = d >> 6, dl = d & 63;
    int slot = (dl >> 3) ^ (k & 7);
    int e = dl & 7;  // 0 or 4
    size_t base = (size_t)tile * 8192 + k * 64 + slot * 8 + e;
    uint2 p;
    p.x = pack2(v.x, v.y);
    p.y = pack2(v.z, v.w);
    *(uint2*)&Wp[base] = p;
  } else if (gb < 80) {
    __shared__ float sc[256];
    int b = gb - 64;
    const float* row = dt + (size_t)b * TT;
    float* orow = ct + (size_t)b * TT;
    float loc[16];
    float s = 0.f;
    int base = tid * 16;
    for (int i = 0; i < 16; ++i) { s += row[base + i]; loc[i] = s; }
    sc[tid] = s;
    __syncthreads();
    for (int off = 1; off < 256; off <<= 1) {
      float v = (tid >= off) ? sc[tid - off] : 0.f;
      __syncthreads();
      sc[tid] += v;
      __syncthreads();
    }
    float excl = sc[tid] - s;
    for (int i = 0; i < 16; ++i) orow[base + i] = excl + loc[i];
  } else {
    __shared__ float su[KK];
    __shared__ float sv[DDIM];
    __shared__ float red[4];
    __shared__ float s_sig;
    if (tid < KK) su[tid] = u_sn[tid];
    __syncthreads();
    for (int rep = 0; rep < 2; ++rep) {
      int d = tid + rep * 256;
      float acc = 0.f;
      for (int k = 0; k < KK; ++k) acc += W[k * DDIM + d] * su[k];
      sv[d] = acc;
    }
    __syncthreads();
    float nn = 0.f;
    for (int rep = 0; rep < 2; ++rep) { float v = sv[tid + rep * 256]; nn += v * v; }
    for (int off = 32; off > 0; off >>= 1) nn += __shfl_down(nn, off, 64);
    if ((tid & 63) == 0) red[tid >> 6] = nn;
    __syncthreads();
    float vn2 = red[0] + red[1] + red[2] + red[3];
    __syncthreads();
    float vinv = 1.f / (sqrtf(vn2) + 1e-6f);
    for (int rep = 0; rep < 2; ++rep) sv[tid + rep * 256] *= vinv;
    __syncthreads();
    float wv = 0.f;
    if (tid < KK) {
      const float* wrow = W + (size_t)tid * DDIM;
      for (int d = 0; d < DDIM; ++d) wv += wrow[d] * sv[d];
    }
    float q = wv * wv;
    for (int off = 32; off > 0; off >>= 1) q += __shfl_down(q, off, 64);
    if ((tid & 63) == 0) red[tid >> 6] = q;
    __syncthreads();
    if (tid == 0) {
      float wn2 = red[0] + red[1] + red[2] + red[3];
      s_sig = wn2 / (sqrtf(wn2) + 1e-6f);
    }
    __syncthreads();
    if (tid < KK) {
      float inv_sigma = 1.f / s_sig;
      float sr = s_real_raw[tid];
      float alpha = ((sr > 20.f) ? sr : log1pf(expf(sr))) + 1e-6f;
      float om = fminf(fmaxf(s_imag[tid], -PI_F), PI_F);
      float bg = expf(b_log[tid]);
      params[tid] = alpha;
      params[KK + tid] = om;
      params[2 * KK + tid] = bg * inv_sigma;
      params[3 * KK + tid] = bg * bias[tid];
    }
  }
}

// ---------------- kernel A: counted-vmcnt pipelined GEMM -> itv (bf16) + chunk totals ----------------
// One s_barrier per iter; W(j+1) DMA + x(j+2) reg-prefetch stay in flight across it.
// vmcnt(4) completes exactly {x(j+1), W(j+1)} before the pack+barrier.
__global__ __launch_bounds__(512, 4) void k_gemm(
    const float* __restrict__ x, const u16* __restrict__ Wp,
    const float* __restrict__ dt, const float* __restrict__ ct,
    const float* __restrict__ params, u16* __restrict__ itvb,
    float* __restrict__ csum_re, float* __restrict__ csum_im) {
  __shared__ __align__(16) u16 smem[32768];   // 64 KB
  // u16 offsets: Xbuf0 @0, Xbuf1 @8192, Wbuf0 @16384, Wbuf1 @24576

  const int chunk = blockIdx.x, b = blockIdx.y;
  const int tid = threadIdx.x;
  const int wv = tid >> 6, l = tid & 63;
  const int lm = l & 15, lg = l >> 4;
  const int kw = wv & 1, tw = wv >> 1;
  const int t0 = chunk * TCB;

  const int xr = tid >> 2, xq = (tid & 3) * 16;
  const size_t xbase = ((size_t)b * TT + t0 + xr) * DDIM + xq;
  const int xs0 = ((xq >> 3) ^ (xr & 7)) * 8;
  const int xs1 = (((xq >> 3) + 1) ^ (xr & 7)) * 8;

  f32x4 acc[2][4];
#pragma unroll
  for (int m = 0; m < 2; ++m)
#pragma unroll
    for (int n = 0; n < 4; ++n) acc[m][n] = (f32x4)(0.0f);

  float4 xa[4], xb[4];
  const char* wsrc = (const char*)Wp + (size_t)tid * 16;
  char* wd0 = (char*)smem + 32768 + tid * 16;   // Wbuf0 slice
  char* wd1 = wd0 + 16384;                      // Wbuf1 slice

  // ---- prologue: W0,x0 | W1,x1 | wait 6 | pack x0 | barrier
  {
    gload_lds16(wsrc, wd0);
    gload_lds16(wsrc + 8192, wd0 + 8192);
    const float* xp = x + xbase;
    xa[0] = *(const float4*)(xp + 0);
    xa[1] = *(const float4*)(xp + 4);
    xa[2] = *(const float4*)(xp + 8);
    xa[3] = *(const float4*)(xp + 12);
    gload_lds16(wsrc + 16384, wd1);
    gload_lds16(wsrc + 16384 + 8192, wd1 + 8192);
    const float* xp1 = x + xbase + 64;
    xb[0] = *(const float4*)(xp1 + 0);
    xb[1] = *(const float4*)(xp1 + 4);
    xb[2] = *(const float4*)(xp1 + 8);
    xb[3] = *(const float4*)(xp1 + 12);
    __builtin_amdgcn_sched_barrier(0);
    asm volatile("s_waitcnt vmcnt(6)" ::: "memory");   // W0, x0 landed
    __builtin_amdgcn_sched_barrier(0);
    *(uint4*)&smem[xr * 64 + xs0] = pack8(xa[0], xa[1]);
    *(uint4*)&smem[xr * 64 + xs1] = pack8(xa[2], xa[3]);
    asm volatile("s_waitcnt lgkmcnt(0)" ::: "memory");
    __builtin_amdgcn_s_barrier();
    __builtin_amdgcn_sched_barrier(0);
  }

#pragma unroll
  for (int j = 0; j < 8; ++j) {
    const int p = j & 1;
    // issue W(j+1) -> Wbuf[p^1]  (W1 already issued in prologue)
    if (j >= 1 && j <= 6) {
      const char* wsg = (const char*)Wp + (size_t)(j + 1) * 16384 + tid * 16;
      char* wd = (char*)smem + 32768 + ((j + 1) & 1) * 16384 + tid * 16;
      gload_lds16(wsg, wd);
      gload_lds16(wsg + 8192, wd + 8192);
    }
    // issue x(j+2) -> regset[j&1]
    if (j <= 5) {
      const float* xp = x + xbase + (size_t)(j + 2) * 64;
      if (p == 0) {
        xa[0] = *(const float4*)(xp + 0);
        xa[1] = *(const float4*)(xp + 4);
        xa[2] = *(const float4*)(xp + 8);
        xa[3] = *(const float4*)(xp + 12);
      } else {
        xb[0] = *(const float4*)(xp + 0);
        xb[1] = *(const float4*)(xp + 4);
        xb[2] = *(const float4*)(xp + 8);
        xb[3] = *(const float4*)(xp + 12);
      }
    }
    __builtin_amdgcn_sched_barrier(0);
    // MFMA on buffers p (published by previous barrier)
    {
      const u16* xbuf = smem + p * 8192;
      const u16* wbuf = smem + 16384 + p * 8192;
#pragma unroll
      for (int ks = 0; ks < 2; ++ks) {
        short8 fa[2], fb[4];
#pragma unroll
        for (int m = 0; m < 2; ++m) {
          int row = tw * 32 + m * 16 + lm;
          int sw = ((ks * 4 + lg) ^ (row & 7)) * 8;
          fa[m] = *(const short8*)&xbuf[row * 64 + sw];
        }
#pragma unroll
        for (int n = 0; n < 4; ++n) {
          int row = kw * 64 + n * 16 + lm;
          int sw = ((ks * 4 + lg) ^ (row & 7)) * 8;
          fb[n] = *(const short8*)&wbuf[row * 64 + sw];
        }
#pragma unroll
        for (int m = 0; m < 2; ++m)
#pragma unroll
          for (int n = 0; n < 4; ++n)
            acc[m][n] = __builtin_amdgcn_mfma_f32_16x16x32_bf16(fa[m], fb[n], acc[m][n], 0, 0, 0);
      }
    }
    __builtin_amdgcn_sched_barrier(0);
    // counted wait: complete x(j+1)+W(j+1); leave x(j+2) in flight. pack, seal, barrier.
    if (j <= 6) {
      if (j == 6) asm volatile("s_waitcnt vmcnt(0)" ::: "memory");
      else        asm volatile("s_waitcnt vmcnt(4)" ::: "memory");
      __builtin_amdgcn_sched_barrier(0);
      u16* xw = smem + (p ^ 1) * 8192;
      if (((j + 1) & 1) == 0) {
        *(uint4*)&xw[xr * 64 + xs0] = pack8(xa[0], xa[1]);
        *(uint4*)&xw[xr * 64 + xs1] = pack8(xa[2], xa[3]);
      } else {
        *(uint4*)&xw[xr * 64 + xs0] = pack8(xb[0], xb[1]);
        *(uint4*)&xw[xr * 64 + xs1] = pack8(xb[2], xb[3]);
      }
      asm volatile("s_waitcnt lgkmcnt(0)" ::: "memory");
      __builtin_amdgcn_s_barrier();
      __builtin_amdgcn_sched_barrier(0);
    }
  }
  __syncthreads();   // iter-7 MFMA reads Xbuf1/Wbuf1; epilogue litv aliases them

  // ---- epilogue: itv -> LDS (bf16) + rotated chunk-total reduce
  float* totr = (float*)smem;          // [4][128]  bytes 0..2048
  float* toti = (float*)smem + 512;    // bytes 2048..4096
  u16* litv = smem + 8192;             // [128 t][128 k] u16, bytes 16384..49152

  float dtv[2][4], ctv[2][4];
#pragma unroll
  for (int m = 0; m < 2; ++m)
#pragma unroll
    for (int r = 0; r < 4; ++r) {
      int t = t0 + tw * 32 + m * 16 + lg * 4 + r;
      dtv[m][r] = dt[(size_t)b * TT + t];
      ctv[m][r] = ct[(size_t)b * TT + t];
    }

#pragma unroll
  for (int n = 0; n < 4; ++n) {
    int k = kw * 64 + n * 16 + lm;
    float pal = params[k], pom = params[KK + k];
    float pc1 = params[2 * KK + k], pc2 = params[3 * KK + k];
    float sr = 0.f, si2 = 0.f;
#pragma unroll
    for (int m = 0; m < 2; ++m)
#pragma unroll
      for (int r = 0; r < 4; ++r) {
        float g = acc[m][n][r];
        float a = pal * dtv[m][r];
        float omr = a * (1.f - a * (0.5f - a * (1.f / 6.f)));  // 1 - exp(-a)
        float itv = omr * (pc1 * g + pc2);
        int tl = tw * 32 + m * 16 + lg * 4 + r;
        litv[tl * KK + k] = (u16)cvt_bf16_rn(itv);
        float e = __expf(pal * ctv[m][r]);
        float sn, cs;
        __sincosf(pom * ctv[m][r], &sn, &cs);
        sr += itv * e * cs;
        si2 -= itv * e * sn;
      }
    sr += __shfl_xor(sr, 16, 64);
    sr += __shfl_xor(sr, 32, 64);
    si2 += __shfl_xor(si2, 16, 64);
    si2 += __shfl_xor(si2, 32, 64);
    if (lg == 0) { totr[tw * KK + k] = sr; toti[tw * KK + k] = si2; }
  }
  __syncthreads();

  // chunk totals (plain stores; dispatch boundary syncs with kernel B)
  if (tid < 256) {
    int v = tid & 127;
    float* src = (tid < 128) ? totr : toti;
    float* dst = (tid < 128) ? csum_re : csum_im;
    dst[((size_t)b * NCB + chunk) * KK + v] =
        (src[v] + src[KK + v]) + (src[2 * KK + v] + src[3 * KK + v]);
  }
  // itv coalesced store: 16 threads x 16B per row, 32 rows per round, 4 rounds
  {
    int row = tid >> 4;          // 0..31
    int c8 = (tid & 15) * 8;     // u16 offset
#pragma unroll
    for (int rr = 0; rr < 4; ++rr) {
      int tr = rr * 32 + row;
      uint4 v = *(const uint4*)&litv[tr * KK + c8];
      *(uint4*)&itvb[((size_t)b * TT + t0 + tr) * KK + c8] = v;
    }
  }
}

// ---------------- kernel B: prefix + 2-pass scan + rotate + vectorized store ----------------
// 4 k per thread (uint2 itv loads, float4 out stores); 16 t-segments x 8 t.
__global__ __launch_bounds__(512) void k_final(
    const u16* __restrict__ itvb, const float* __restrict__ ct,
    const float* __restrict__ params,
    const float* __restrict__ csum_re, const float* __restrict__ csum_im,
    float* __restrict__ out) {
  __shared__ float prer[KK], prei[KK];
  __shared__ float segr[16][KK], segi[16][KK];
  const int chunk = blockIdx.x, b = blockIdx.y;
  const int tid = threadIdx.x;
  const int k4 = (tid & 31) * 4, tseg = tid >> 5;   // 16 segments x 8 t
  const int tbase = chunk * TCB + tseg * 8;

  // cross-chunk prefix (csum written by kernel A; dispatch boundary = visible)
  if (tid < 256) {
    int v = tid & 127;
    const float* srcp = (tid < 128) ? csum_re : csum_im;
    float* dstp = (tid < 128) ? prer : prei;
    size_t base = (size_t)b * NCB * KK + v;
    float a0 = 0.f, a1 = 0.f, a2 = 0.f, a3 = 0.f;
    int c = 0;
    for (; c + 4 <= chunk; c += 4) {
      a0 += srcp[base + (size_t)(c + 0) * KK];
      a1 += srcp[base + (size_t)(c + 1) * KK];
      a2 += srcp[base + (size_t)(c + 2) * KK];
      a3 += srcp[base + (size_t)(c + 3) * KK];
    }
    for (; c < chunk; ++c) a0 += srcp[base + (size_t)c * KK];
    dstp[v] = (a0 + a1) + (a2 + a3);
  }

  float4 pal4 = *(const float4*)&params[k4];
  float4 pom4 = *(const float4*)&params[KK + k4];
  float pal[4] = {pal4.x, pal4.y, pal4.z, pal4.w};
  float pom[4] = {pom4.x, pom4.y, pom4.z, pom4.w};

  // pass 1: segment totals
  float sr[4] = {0.f, 0.f, 0.f, 0.f}, si[4] = {0.f, 0.f, 0.f, 0.f};
#pragma unroll
  for (int i = 0; i < 8; ++i) {
    int t = tbase + i;
    float ctv = ct[(size_t)b * TT + t];
    uint2 iv = *(const uint2*)&itvb[((size_t)b * TT + t) * KK + k4];
    float it[4] = {__uint_as_float(iv.x << 16), __uint_as_float(iv.x & 0xFFFF0000u),
                   __uint_as_float(iv.y << 16), __uint_as_float(iv.y & 0xFFFF0000u)};
#pragma unroll
    for (int c = 0; c < 4; ++c) {
      float e = __expf(pal[c] * ctv);
      float sn, cs;
      __sincosf(pom[c] * ctv, &sn, &cs);
      sr[c] += it[c] * e * cs;
      si[c] -= it[c] * e * sn;
    }
  }
  *(float4*)&segr[tseg][k4] = make_float4(sr[0], sr[1], sr[2], sr[3]);
  *(float4*)&segi[tseg][k4] = make_float4(si[0], si[1], si[2], si[3]);
  __syncthreads();
  float cr[4], ci[4];
  {
    float4 p0 = *(const float4*)&prer[k4];
    float4 p1 = *(const float4*)&prei[k4];
    cr[0] = p0.x; cr[1] = p0.y; cr[2] = p0.z; cr[3] = p0.w;
    ci[0] = p1.x; ci[1] = p1.y; ci[2] = p1.z; ci[3] = p1.w;
  }
  for (int s = 0; s < tseg; ++s) {
    float4 a = *(const float4*)&segr[s][k4];
    float4 bb = *(const float4*)&segi[s][k4];
    cr[0] += a.x; cr[1] += a.y; cr[2] += a.z; cr[3] += a.w;
    ci[0] += bb.x; ci[1] += bb.y; ci[2] += bb.z; ci[3] += bb.w;
  }
  // pass 2: inclusive scan + rotate + store (16B/lane coalesced)
#pragma unroll
  for (int i = 0; i < 8; ++i) {
    int t = tbase + i;
    float ctv = ct[(size_t)b * TT + t];
    uint2 iv = *(const uint2*)&itvb[((size_t)b * TT + t) * KK + k4];
    float it[4] = {__uint_as_float(iv.x << 16), __uint_as_float(iv.x & 0xFFFF0000u),
                   __uint_as_float(iv.y << 16), __uint_as_float(iv.y & 0xFFFF0000u)};
    float C4[4], S4[4];
#pragma unroll
    for (int c = 0; c < 4; ++c) {
      float e = __expf(pal[c] * ctv);
      float sn, cs;
      __sincosf(pom[c] * ctv, &sn, &cs);
      cr[c] += it[c] * e * cs;
      ci[c] -= it[c] * e * sn;
      float dec = __builtin_amdgcn_rcpf(e);   // e^{-alpha*ct}
      float Rw = dec * (cs * cr[c] - sn * ci[c]);
      float Iw = dec * (cs * ci[c] + sn * cr[c]);
      C4[c] = Rw - Iw;
      S4[c] = Rw + Iw;
    }
    size_t rowb = ((size_t)b * TT + t) * (2 * KK);
    *(float4*)&out[rowb + k4] = make_float4(C4[0], C4[1], C4[2], C4[3]);
    *(float4*)&out[rowb + KK + k4] = make_float4(S4[0], S4[1], S4[2], S4[3]);
  }
}

extern "C" void kernel_launch(void* const* d_in, const int* in_sizes, int n_in,
                              void* d_out, int out_size, void* d_ws, size_t ws_size,
                              hipStream_t stream) {
  const float* x    = (const float*)d_in[0];
  const float* dt   = (const float*)d_in[1];
  const float* srr  = (const float*)d_in[2];
  const float* si   = (const float*)d_in[3];
  const float* W    = (const float*)d_in[4];
  const float* bias = (const float*)d_in[5];
  const float* blog = (const float*)d_in[6];
  const float* usn  = (const float*)d_in[7];
  float* out = (float*)d_out;
  float* ws = (float*)d_ws;

  float* params  = ws;                          // 512 f
  float* ct      = ws + 4 * KK;                 // 65536 f
  float* csum_re = ct + (size_t)BB * TT;        // 65536 f
  float* csum_im = csum_re + (size_t)BB * NCB * KK;  // 65536 f
  u16*   Wp      = (u16*)(csum_im + (size_t)BB * NCB * KK);  // 65536 u16
  u16*   itvb    = Wp + 65536;                  // B*T*K u16 = 16 MB

  k_prep<<<81, 256, 0, stream>>>(W, usn, srr, si, bias, blog, dt, params, Wp, ct);
  k_gemm<<<dim3(NCB, BB), 512, 0, stream>>>(x, Wp, dt, ct, params, itvb,
                                            csum_re, csum_im);
  k_final<<<dim3(NCB, BB), 512, 0, stream>>>(itvb, ct, params,
                                             csum_re, csum_im, out);
}

// Round 12
// 67.520 us; speedup vs baseline: 1.0542x; 1.0542x over previous
//
#include <hip/hip_runtime.h>
#include <stdint.h>

#define BB 16
#define TT 4096
#define DDIM 512
#define KK 128
#define TCB 128            // t-rows per chunk
#define NCB (TT / TCB)     // 32 chunks
#define PI_F 3.14159265358979323846f

typedef unsigned short u16;
typedef __attribute__((ext_vector_type(8))) short short8;
typedef __attribute__((ext_vector_type(4))) float f32x4;

__device__ __forceinline__ uint32_t cvt_bf16_rn(float f) {
  uint32_t u = __float_as_uint(f);
  return (u + 0x7FFFu + ((u >> 16) & 1u)) >> 16;
}
__device__ __forceinline__ uint32_t pack2(float a, float b) {
  return cvt_bf16_rn(a) | (cvt_bf16_rn(b) << 16);
}
__device__ __forceinline__ uint4 pack8(const float4 f0, const float4 f1) {
  uint4 r;
  r.x = pack2(f0.x, f0.y);
  r.y = pack2(f0.z, f0.w);
  r.z = pack2(f1.x, f1.y);
  r.w = pack2(f1.z, f1.w);
  return r;
}
__device__ __forceinline__ void gload_lds16(const void* g, void* l) {
  __builtin_amdgcn_global_load_lds(
      (const __attribute__((address_space(1))) void*)g,
      (__attribute__((address_space(3))) void*)l, 16, 0, 0);
}

// ---------------- kernel 0: fused prep (wpack | ct | params) ----------------
__global__ __launch_bounds__(256) void k_prep(
    const float* __restrict__ W, const float* __restrict__ u_sn,
    const float* __restrict__ s_real_raw, const float* __restrict__ s_imag,
    const float* __restrict__ bias, const float* __restrict__ b_log,
    const float* __restrict__ dt,
    float* __restrict__ params, u16* __restrict__ Wp, float* __restrict__ ct) {
  int gb = blockIdx.x;
  int tid = threadIdx.x;
  if (gb < 64) {
    int idx = gb * 256 + tid;
    int k = idx >> 7;
    int d = (idx & 127) * 4;
    float4 v = *(const float4*)&W[(size_t)k * DDIM + d];
    int tile = d >> 6, dl = d & 63;
    int slot = (dl >> 3) ^ (k & 7);
    int e = dl & 7;  // 0 or 4
    size_t base = (size_t)tile * 8192 + k * 64 + slot * 8 + e;
    uint2 p;
    p.x = pack2(v.x, v.y);
    p.y = pack2(v.z, v.w);
    *(uint2*)&Wp[base] = p;
  } else if (gb < 80) {
    __shared__ float sc[256];
    int b = gb - 64;
    const float* row = dt + (size_t)b * TT;
    float* orow = ct + (size_t)b * TT;
    float loc[16];
    float s = 0.f;
    int base = tid * 16;
    for (int i = 0; i < 16; ++i) { s += row[base + i]; loc[i] = s; }
    sc[tid] = s;
    __syncthreads();
    for (int off = 1; off < 256; off <<= 1) {
      float v = (tid >= off) ? sc[tid - off] : 0.f;
      __syncthreads();
      sc[tid] += v;
      __syncthreads();
    }
    float excl = sc[tid] - s;
    for (int i = 0; i < 16; ++i) orow[base + i] = excl + loc[i];
  } else {
    __shared__ float su[KK];
    __shared__ float sv[DDIM];
    __shared__ float red[4];
    __shared__ float wred[256];
    __shared__ float s_sig;
    if (tid < KK) su[tid] = u_sn[tid];
    __syncthreads();
    for (int rep = 0; rep < 2; ++rep) {
      int d = tid + rep * 256;
      float acc = 0.f;
      for (int k = 0; k < KK; ++k) acc += W[k * DDIM + d] * su[k];
      sv[d] = acc;
    }
    __syncthreads();
    float nn = 0.f;
    for (int rep = 0; rep < 2; ++rep) { float v = sv[tid + rep * 256]; nn += v * v; }
    for (int off = 32; off > 0; off >>= 1) nn += __shfl_down(nn, off, 64);
    if ((tid & 63) == 0) red[tid >> 6] = nn;
    __syncthreads();
    float vn2 = red[0] + red[1] + red[2] + red[3];
    __syncthreads();
    float vinv = 1.f / (sqrtf(vn2) + 1e-6f);
    for (int rep = 0; rep < 2; ++rep) sv[tid + rep * 256] *= vinv;
    __syncthreads();
    // Wv: 2 threads per k-row, 256 d's each, LDS combine
    {
      int k = tid & 127, q = tid >> 7;
      const float* wrow = W + (size_t)k * DDIM + q * 256;
      float p = 0.f;
      for (int d = 0; d < 256; ++d) p += wrow[d] * sv[q * 256 + d];
      wred[tid] = p;
    }
    __syncthreads();
    float wv = 0.f;
    if (tid < KK) wv = wred[tid] + wred[tid + 128];
    float q = wv * wv;
    for (int off = 32; off > 0; off >>= 1) q += __shfl_down(q, off, 64);
    if ((tid & 63) == 0) red[tid >> 6] = q;
    __syncthreads();
    if (tid == 0) {
      float wn2 = red[0] + red[1] + red[2] + red[3];
      s_sig = wn2 / (sqrtf(wn2) + 1e-6f);
    }
    __syncthreads();
    if (tid < KK) {
      float inv_sigma = 1.f / s_sig;
      float sr = s_real_raw[tid];
      float alpha = ((sr > 20.f) ? sr : log1pf(expf(sr))) + 1e-6f;
      float om = fminf(fmaxf(s_imag[tid], -PI_F), PI_F);
      float bg = expf(b_log[tid]);
      params[tid] = alpha;
      params[KK + tid] = om;
      params[2 * KK + tid] = bg * inv_sigma;
      params[3 * KK + tid] = bg * bias[tid];
    }
  }
}

// ---------------- kernel A: pipelined GEMM -> itv (bf16) + chunk totals ----------------
// R10-proven structure: per-iter dbuf, issue-next -> MFMA -> pack, one __syncthreads.
__global__ __launch_bounds__(512, 4) void k_gemm(
    const float* __restrict__ x, const u16* __restrict__ Wp,
    const float* __restrict__ dt, const float* __restrict__ ct,
    const float* __restrict__ params, u16* __restrict__ itvb,
    float* __restrict__ csum_re, float* __restrict__ csum_im) {
  __shared__ __align__(16) u16 smem[32768];   // 64 KB
  // u16 offsets: Xbuf0 @0, Xbuf1 @8192, Wbuf0 @16384, Wbuf1 @24576

  const int chunk = blockIdx.x, b = blockIdx.y;
  const int tid = threadIdx.x;
  const int wv = tid >> 6, l = tid & 63;
  const int lm = l & 15, lg = l >> 4;
  const int kw = wv & 1, tw = wv >> 1;
  const int t0 = chunk * TCB;

  const int xr = tid >> 2, xq = (tid & 3) * 16;
  const size_t xbase = ((size_t)b * TT + t0 + xr) * DDIM + xq;
  const int xs0 = ((xq >> 3) ^ (xr & 7)) * 8;
  const int xs1 = (((xq >> 3) + 1) ^ (xr & 7)) * 8;

  f32x4 acc[2][4];
#pragma unroll
  for (int m = 0; m < 2; ++m)
#pragma unroll
    for (int n = 0; n < 4; ++n) acc[m][n] = (f32x4)(0.0f);

  // ---- prologue: stage tile 0 into buffer 0
  {
    const char* wsg = (const char*)Wp + (size_t)tid * 16;
    char* wd = (char*)smem + 32768 + tid * 16;
    gload_lds16(wsg, wd);
    gload_lds16(wsg + 8192, wd + 8192);
    const float* xp = x + xbase;
    float4 f0 = *(const float4*)(xp + 0);
    float4 f1 = *(const float4*)(xp + 4);
    float4 f2 = *(const float4*)(xp + 8);
    float4 f3 = *(const float4*)(xp + 12);
    *(uint4*)&smem[xr * 64 + xs0] = pack8(f0, f1);
    *(uint4*)&smem[xr * 64 + xs1] = pack8(f2, f3);
  }
  __syncthreads();

  int cur = 0;
  for (int it = 0; it < 8; ++it) {
    float4 f0, f1, f2, f3;
    // phase 1: issue next-tile loads (x -> regs, W -> LDS via DMA)
    if (it < 7) {
      const float* xp = x + xbase + (it + 1) * 64;
      f0 = *(const float4*)(xp + 0);
      f1 = *(const float4*)(xp + 4);
      f2 = *(const float4*)(xp + 8);
      f3 = *(const float4*)(xp + 12);
      const char* wsg = (const char*)Wp + (size_t)(it + 1) * 16384 + tid * 16;
      char* wd = (char*)smem + 32768 + (cur ^ 1) * 16384 + tid * 16;
      gload_lds16(wsg, wd);
      gload_lds16(wsg + 8192, wd + 8192);
    }
    __builtin_amdgcn_sched_barrier(0);
    // phase 2: MFMA on current buffers
    {
      const u16* xb = smem + cur * 8192;
      const u16* wb = smem + 16384 + cur * 8192;
#pragma unroll
      for (int ks = 0; ks < 2; ++ks) {
        short8 fa[2], fb[4];
#pragma unroll
        for (int m = 0; m < 2; ++m) {
          int row = tw * 32 + m * 16 + lm;
          int sw = ((ks * 4 + lg) ^ (row & 7)) * 8;
          fa[m] = *(const short8*)&xb[row * 64 + sw];
        }
#pragma unroll
        for (int n = 0; n < 4; ++n) {
          int row = kw * 64 + n * 16 + lm;
          int sw = ((ks * 4 + lg) ^ (row & 7)) * 8;
          fb[n] = *(const short8*)&wb[row * 64 + sw];
        }
#pragma unroll
        for (int m = 0; m < 2; ++m)
#pragma unroll
          for (int n = 0; n < 4; ++n)
            acc[m][n] = __builtin_amdgcn_mfma_f32_16x16x32_bf16(fa[m], fb[n], acc[m][n], 0, 0, 0);
      }
    }
    __builtin_amdgcn_sched_barrier(0);
    // phase 3: convert prefetched x, write to next buffer
    if (it < 7) {
      u16* xb = smem + (cur ^ 1) * 8192;
      *(uint4*)&xb[xr * 64 + xs0] = pack8(f0, f1);
      *(uint4*)&xb[xr * 64 + xs1] = pack8(f2, f3);
    }
    __syncthreads();
    cur ^= 1;
  }

  // ---- epilogue: itv -> LDS (bf16) + rotated chunk-total reduce
  float* totr = (float*)smem;          // [4][128]  bytes 0..2048
  float* toti = (float*)smem + 512;    // bytes 2048..4096
  u16* litv = smem + 8192;             // [128 t][128 k] u16, bytes 16384..49152

  float dtv[2][4], ctv[2][4];
#pragma unroll
  for (int m = 0; m < 2; ++m)
#pragma unroll
    for (int r = 0; r < 4; ++r) {
      int t = t0 + tw * 32 + m * 16 + lg * 4 + r;
      dtv[m][r] = dt[(size_t)b * TT + t];
      ctv[m][r] = ct[(size_t)b * TT + t];
    }

#pragma unroll
  for (int n = 0; n < 4; ++n) {
    int k = kw * 64 + n * 16 + lm;
    float pal = params[k], pom = params[KK + k];
    float pc1 = params[2 * KK + k], pc2 = params[3 * KK + k];
    float sr = 0.f, si2 = 0.f;
#pragma unroll
    for (int m = 0; m < 2; ++m)
#pragma unroll
      for (int r = 0; r < 4; ++r) {
        float g = acc[m][n][r];
        float a = pal * dtv[m][r];
        float omr = a * (1.f - a * (0.5f - a * (1.f / 6.f)));  // 1 - exp(-a)
        float itv = omr * (pc1 * g + pc2);
        int tl = tw * 32 + m * 16 + lg * 4 + r;
        litv[tl * KK + k] = (u16)cvt_bf16_rn(itv);
        float e = __expf(pal * ctv[m][r]);
        float sn, cs;
        __sincosf(pom * ctv[m][r], &sn, &cs);
        sr += itv * e * cs;
        si2 -= itv * e * sn;
      }
    sr += __shfl_xor(sr, 16, 64);
    sr += __shfl_xor(sr, 32, 64);
    si2 += __shfl_xor(si2, 16, 64);
    si2 += __shfl_xor(si2, 32, 64);
    if (lg == 0) { totr[tw * KK + k] = sr; toti[tw * KK + k] = si2; }
  }
  __syncthreads();

  // chunk totals (plain stores; dispatch boundary syncs with kernel B)
  if (tid < 256) {
    int v = tid & 127;
    float* src = (tid < 128) ? totr : toti;
    float* dst = (tid < 128) ? csum_re : csum_im;
    dst[((size_t)b * NCB + chunk) * KK + v] =
        (src[v] + src[KK + v]) + (src[2 * KK + v] + src[3 * KK + v]);
  }
  // itv coalesced store: 16 threads x 16B per row, 32 rows per round, 4 rounds
  {
    int row = tid >> 4;          // 0..31
    int c8 = (tid & 15) * 8;     // u16 offset
#pragma unroll
    for (int rr = 0; rr < 4; ++rr) {
      int tr = rr * 32 + row;
      uint4 v = *(const uint4*)&litv[tr * KK + c8];
      *(uint4*)&itvb[((size_t)b * TT + t0 + tr) * KK + c8] = v;
    }
  }
}

// ---------------- kernel B: prefix + single-trig scan + algebraic rotate ----------------
// Pass 1 computes F = e^{alpha*ct}(cos - i sin) per element, keeps fr/fi + itv in regs.
// Pass 2: zero transcendentals — rotation = S * conj(F) / |F|^2, |F|^2 = fr^2+fi^2.
__global__ __launch_bounds__(512) void k_final(
    const u16* __restrict__ itvb, const float* __restrict__ ct,
    const float* __restrict__ params,
    const float* __restrict__ csum_re, const float* __restrict__ csum_im,
    float* __restrict__ out) {
  __shared__ float prer[KK], prei[KK];
  __shared__ float segr[16][KK], segi[16][KK];
  const int chunk = blockIdx.x, b = blockIdx.y;
  const int tid = threadIdx.x;
  const int k4 = (tid & 31) * 4, tseg = tid >> 5;   // 16 segments x 8 t
  const int tbase = chunk * TCB + tseg * 8;

  // cross-chunk prefix (csum written by kernel A; dispatch boundary = visible)
  if (tid < 256) {
    int v = tid & 127;
    const float* srcp = (tid < 128) ? csum_re : csum_im;
    float* dstp = (tid < 128) ? prer : prei;
    size_t base = (size_t)b * NCB * KK + v;
    float a0 = 0.f, a1 = 0.f, a2 = 0.f, a3 = 0.f;
    int c = 0;
    for (; c + 4 <= chunk; c += 4) {
      a0 += srcp[base + (size_t)(c + 0) * KK];
      a1 += srcp[base + (size_t)(c + 1) * KK];
      a2 += srcp[base + (size_t)(c + 2) * KK];
      a3 += srcp[base + (size_t)(c + 3) * KK];
    }
    for (; c < chunk; ++c) a0 += srcp[base + (size_t)c * KK];
    dstp[v] = (a0 + a1) + (a2 + a3);
  }

  float4 pal4 = *(const float4*)&params[k4];
  float4 pom4 = *(const float4*)&params[KK + k4];
  float pal[4] = {pal4.x, pal4.y, pal4.z, pal4.w};
  float pom[4] = {pom4.x, pom4.y, pom4.z, pom4.w};

  uint2 iv8[8];
  float fr[8][4], fi[8][4];
  float sr[4] = {0.f, 0.f, 0.f, 0.f}, si[4] = {0.f, 0.f, 0.f, 0.f};
#pragma unroll
  for (int i = 0; i < 8; ++i) {
    int t = tbase + i;
    float ctv = ct[(size_t)b * TT + t];
    iv8[i] = *(const uint2*)&itvb[((size_t)b * TT + t) * KK + k4];
    float it[4] = {__uint_as_float(iv8[i].x << 16), __uint_as_float(iv8[i].x & 0xFFFF0000u),
                   __uint_as_float(iv8[i].y << 16), __uint_as_float(iv8[i].y & 0xFFFF0000u)};
#pragma unroll
    for (int c = 0; c < 4; ++c) {
      float e = __expf(pal[c] * ctv);
      float sn, cs;
      __sincosf(pom[c] * ctv, &sn, &cs);
      fr[i][c] = e * cs;
      fi[i][c] = e * sn;
      sr[c] += it[c] * fr[i][c];
      si[c] -= it[c] * fi[i][c];
    }
  }
  *(float4*)&segr[tseg][k4] = make_float4(sr[0], sr[1], sr[2], sr[3]);
  *(float4*)&segi[tseg][k4] = make_float4(si[0], si[1], si[2], si[3]);
  __syncthreads();
  float cr[4], ci[4];
  {
    float4 p0 = *(const float4*)&prer[k4];
    float4 p1 = *(const float4*)&prei[k4];
    cr[0] = p0.x; cr[1] = p0.y; cr[2] = p0.z; cr[3] = p0.w;
    ci[0] = p1.x; ci[1] = p1.y; ci[2] = p1.z; ci[3] = p1.w;
  }
  for (int s = 0; s < tseg; ++s) {
    float4 a = *(const float4*)&segr[s][k4];
    float4 bb = *(const float4*)&segi[s][k4];
    cr[0] += a.x; cr[1] += a.y; cr[2] += a.z; cr[3] += a.w;
    ci[0] += bb.x; ci[1] += bb.y; ci[2] += bb.z; ci[3] += bb.w;
  }
  // pass 2: scan + algebraic rotation (no transcendentals)
#pragma unroll
  for (int i = 0; i < 8; ++i) {
    int t = tbase + i;
    float it[4] = {__uint_as_float(iv8[i].x << 16), __uint_as_float(iv8[i].x & 0xFFFF0000u),
                   __uint_as_float(iv8[i].y << 16), __uint_as_float(iv8[i].y & 0xFFFF0000u)};
    float C4[4], S4[4];
#pragma unroll
    for (int c = 0; c < 4; ++c) {
      float f_r = fr[i][c], f_i = fi[i][c];
      cr[c] += it[c] * f_r;
      ci[c] -= it[c] * f_i;
      float inv = __builtin_amdgcn_rcpf(f_r * f_r + f_i * f_i);   // 1/e^2
      float Rw = (cr[c] * f_r - ci[c] * f_i) * inv;
      float Iw = (cr[c] * f_i + ci[c] * f_r) * inv;
      C4[c] = Rw - Iw;
      S4[c] = Rw + Iw;
    }
    size_t rowb = ((size_t)b * TT + t) * (2 * KK);
    *(float4*)&out[rowb + k4] = make_float4(C4[0], C4[1], C4[2], C4[3]);
    *(float4*)&out[rowb + KK + k4] = make_float4(S4[0], S4[1], S4[2], S4[3]);
  }
}

extern "C" void kernel_launch(void* const* d_in, const int* in_sizes, int n_in,
                              void* d_out, int out_size, void* d_ws, size_t ws_size,
                              hipStream_t stream) {
  const float* x    = (const float*)d_in[0];
  const float* dt   = (const float*)d_in[1];
  const float* srr  = (const float*)d_in[2];
  const float* si   = (const float*)d_in[3];
  const float* W    = (const float*)d_in[4];
  const float* bias = (const float*)d_in[5];
  const float* blog = (const float*)d_in[6];
  const float* usn  = (const float*)d_in[7];
  float* out = (float*)d_out;
  float* ws = (float*)d_ws;

  float* params  = ws;                          // 512 f
  float* ct      = ws + 4 * KK;                 // 65536 f
  float* csum_re = ct + (size_t)BB * TT;        // 65536 f
  float* csum_im = csum_re + (size_t)BB * NCB * KK;  // 65536 f
  u16*   Wp      = (u16*)(csum_im + (size_t)BB * NCB * KK);  // 65536 u16
  u16*   itvb    = Wp + 65536;                  // B*T*K u16 = 16 MB

  k_prep<<<81, 256, 0, stream>>>(W, usn, srr, si, bias, blog, dt, params, Wp, ct);
  k_gemm<<<dim3(NCB, BB), 512, 0, stream>>>(x, Wp, dt, ct, params, itvb,
                                            csum_re, csum_im);
  k_final<<<dim3(NCB, BB), 512, 0, stream>>>(itvb, ct, params,
                                             csum_re, csum_im, out);
}

// Round 13
// 67.440 us; speedup vs baseline: 1.0554x; 1.0012x over previous
//
#include <hip/hip_runtime.h>
#include <stdint.h>

#define BB 16
#define TT 4096
#define DDIM 512
#define KK 128
#define TCB 128            // t-rows per chunk
#define NCB (TT / TCB)     // 32 chunks
#define PI_F 3.14159265358979323846f

typedef unsigned short u16;
typedef __attribute__((ext_vector_type(8))) short short8;
typedef __attribute__((ext_vector_type(4))) float f32x4;

__device__ __forceinline__ uint32_t cvt_bf16_rn(float f) {
  uint32_t u = __float_as_uint(f);
  return (u + 0x7FFFu + ((u >> 16) & 1u)) >> 16;
}
__device__ __forceinline__ uint32_t pack2(float a, float b) {
  return cvt_bf16_rn(a) | (cvt_bf16_rn(b) << 16);
}
__device__ __forceinline__ void gload_lds16(const void* g, void* l) {
  __builtin_amdgcn_global_load_lds(
      (const __attribute__((address_space(1))) void*)g,
      (__attribute__((address_space(3))) void*)l, 16, 0, 0);
}

// ---------------- kernel 0: fused prep (wpack | ct | params) ----------------
__global__ __launch_bounds__(256) void k_prep(
    const float* __restrict__ W, const float* __restrict__ u_sn,
    const float* __restrict__ s_real_raw, const float* __restrict__ s_imag,
    const float* __restrict__ bias, const float* __restrict__ b_log,
    const float* __restrict__ dt,
    float* __restrict__ params, u16* __restrict__ Wp, float* __restrict__ ct) {
  int gb = blockIdx.x;
  int tid = threadIdx.x;
  if (gb < 64) {
    int idx = gb * 256 + tid;
    int k = idx >> 7;
    int d = (idx & 127) * 4;
    float4 v = *(const float4*)&W[(size_t)k * DDIM + d];
    int tile = d >> 6, dl = d & 63;
    int slot = (dl >> 3) ^ (k & 7);
    int e = dl & 7;  // 0 or 4
    size_t base = (size_t)tile * 8192 + k * 64 + slot * 8 + e;
    uint2 p;
    p.x = pack2(v.x, v.y);
    p.y = pack2(v.z, v.w);
    *(uint2*)&Wp[base] = p;
  } else if (gb < 80) {
    __shared__ float sc[256];
    int b = gb - 64;
    const float* row = dt + (size_t)b * TT;
    float* orow = ct + (size_t)b * TT;
    float loc[16];
    float s = 0.f;
    int base = tid * 16;
    for (int i = 0; i < 16; ++i) { s += row[base + i]; loc[i] = s; }
    sc[tid] = s;
    __syncthreads();
    for (int off = 1; off < 256; off <<= 1) {
      float v = (tid >= off) ? sc[tid - off] : 0.f;
      __syncthreads();
      sc[tid] += v;
      __syncthreads();
    }
    float excl = sc[tid] - s;
    for (int i = 0; i < 16; ++i) orow[base + i] = excl + loc[i];
  } else {
    __shared__ float su[KK];
    __shared__ float sv[DDIM];
    __shared__ float red[4];
    __shared__ float wred[256];
    __shared__ float s_sig;
    if (tid < KK) su[tid] = u_sn[tid];
    __syncthreads();
    for (int rep = 0; rep < 2; ++rep) {
      int d = tid + rep * 256;
      float acc = 0.f;
      for (int k = 0; k < KK; ++k) acc += W[k * DDIM + d] * su[k];
      sv[d] = acc;
    }
    __syncthreads();
    float nn = 0.f;
    for (int rep = 0; rep < 2; ++rep) { float v = sv[tid + rep * 256]; nn += v * v; }
    for (int off = 32; off > 0; off >>= 1) nn += __shfl_down(nn, off, 64);
    if ((tid & 63) == 0) red[tid >> 6] = nn;
    __syncthreads();
    float vn2 = red[0] + red[1] + red[2] + red[3];
    __syncthreads();
    float vinv = 1.f / (sqrtf(vn2) + 1e-6f);
    for (int rep = 0; rep < 2; ++rep) sv[tid + rep * 256] *= vinv;
    __syncthreads();
    {
      int k = tid & 127, q = tid >> 7;
      const float* wrow = W + (size_t)k * DDIM + q * 256;
      float p = 0.f;
      for (int d = 0; d < 256; ++d) p += wrow[d] * sv[q * 256 + d];
      wred[tid] = p;
    }
    __syncthreads();
    float wv = 0.f;
    if (tid < KK) wv = wred[tid] + wred[tid + 128];
    float q = wv * wv;
    for (int off = 32; off > 0; off >>= 1) q += __shfl_down(q, off, 64);
    if ((tid & 63) == 0) red[tid >> 6] = q;
    __syncthreads();
    if (tid == 0) {
      float wn2 = red[0] + red[1] + red[2] + red[3];
      s_sig = wn2 / (sqrtf(wn2) + 1e-6f);
    }
    __syncthreads();
    if (tid < KK) {
      float inv_sigma = 1.f / s_sig;
      float sr = s_real_raw[tid];
      float alpha = ((sr > 20.f) ? sr : log1pf(expf(sr))) + 1e-6f;
      float om = fminf(fmaxf(s_imag[tid], -PI_F), PI_F);
      float bg = expf(b_log[tid]);
      params[tid] = alpha;
      params[KK + tid] = om;
      params[2 * KK + tid] = bg * inv_sigma;
      params[3 * KK + tid] = bg * bias[tid];
    }
  }
}

// ---------------- kernel A: pipelined GEMM -> itv (bf16) + chunk totals ----------------
// x loads are wave-contiguous per instruction: thread tid handles rows
// (tid>>4)+32q (q=0..3), chunk (tid&15)*4 f32 -> each instr covers 1 KB
// contiguous per wave (was 16-B chunks at 64-B stride).
__global__ __launch_bounds__(512, 4) void k_gemm(
    const float* __restrict__ x, const u16* __restrict__ Wp,
    const float* __restrict__ dt, const float* __restrict__ ct,
    const float* __restrict__ params, u16* __restrict__ itvb,
    float* __restrict__ csum_re, float* __restrict__ csum_im) {
  __shared__ __align__(16) u16 smem[32768];   // 64 KB
  // u16 offsets: Xbuf0 @0, Xbuf1 @8192, Wbuf0 @16384, Wbuf1 @24576

  const int chunk = blockIdx.x, b = blockIdx.y;
  const int tid = threadIdx.x;
  const int wv = tid >> 6, l = tid & 63;
  const int lm = l & 15, lg = l >> 4;
  const int kw = wv & 1, tw = wv >> 1;
  const int t0 = chunk * TCB;

  // x staging: 4 rows per thread (r = xr0 + 32q), 4 consecutive f32 each
  const int xr0 = tid >> 4;          // 0..31
  const int xc = (tid & 15) * 4;     // f32 offset in row: 0..60
  const size_t xbase = ((size_t)b * TT + t0 + xr0) * DDIM + xc;
  // LDS dest: row xr0+32q, swizzled slot = (xc>>3)^(row&7), half = (xc>>2)&1
  int xso[4];
#pragma unroll
  for (int q = 0; q < 4; ++q) {
    int row = xr0 + 32 * q;
    xso[q] = row * 64 + (((xc >> 3) ^ (row & 7)) << 3) + ((xc >> 2) & 1) * 4;
  }

  f32x4 acc[2][4];
#pragma unroll
  for (int m = 0; m < 2; ++m)
#pragma unroll
    for (int n = 0; n < 4; ++n) acc[m][n] = (f32x4)(0.0f);

  // ---- prologue: stage tile 0 into buffer 0
  {
    const char* wsg = (const char*)Wp + (size_t)tid * 16;
    char* wd = (char*)smem + 32768 + tid * 16;
    gload_lds16(wsg, wd);
    gload_lds16(wsg + 8192, wd + 8192);
#pragma unroll
    for (int q = 0; q < 4; ++q) {
      float4 v = *(const float4*)(x + xbase + (size_t)(32 * q) * DDIM);
      uint2 p;
      p.x = pack2(v.x, v.y);
      p.y = pack2(v.z, v.w);
      *(uint2*)&smem[xso[q]] = p;
    }
  }
  __syncthreads();

  int cur = 0;
  for (int it = 0; it < 8; ++it) {
    float4 xf[4];
    // phase 1: issue next-tile loads (x -> regs wave-contiguous, W -> LDS DMA)
    if (it < 7) {
      const float* xp = x + xbase + (it + 1) * 64;
#pragma unroll
      for (int q = 0; q < 4; ++q)
        xf[q] = *(const float4*)(xp + (size_t)(32 * q) * DDIM);
      const char* wsg = (const char*)Wp + (size_t)(it + 1) * 16384 + tid * 16;
      char* wd = (char*)smem + 32768 + (cur ^ 1) * 16384 + tid * 16;
      gload_lds16(wsg, wd);
      gload_lds16(wsg + 8192, wd + 8192);
    }
    __builtin_amdgcn_sched_barrier(0);
    // phase 2: MFMA on current buffers (setprio raises this block over stagers)
    {
      const u16* xb = smem + cur * 8192;
      const u16* wb = smem + 16384 + cur * 8192;
      __builtin_amdgcn_s_setprio(1);
#pragma unroll
      for (int ks = 0; ks < 2; ++ks) {
        short8 fa[2], fb[4];
#pragma unroll
        for (int m = 0; m < 2; ++m) {
          int row = tw * 32 + m * 16 + lm;
          int sw = ((ks * 4 + lg) ^ (row & 7)) * 8;
          fa[m] = *(const short8*)&xb[row * 64 + sw];
        }
#pragma unroll
        for (int n = 0; n < 4; ++n) {
          int row = kw * 64 + n * 16 + lm;
          int sw = ((ks * 4 + lg) ^ (row & 7)) * 8;
          fb[n] = *(const short8*)&wb[row * 64 + sw];
        }
#pragma unroll
        for (int m = 0; m < 2; ++m)
#pragma unroll
          for (int n = 0; n < 4; ++n)
            acc[m][n] = __builtin_amdgcn_mfma_f32_16x16x32_bf16(fa[m], fb[n], acc[m][n], 0, 0, 0);
      }
      __builtin_amdgcn_s_setprio(0);
    }
    __builtin_amdgcn_sched_barrier(0);
    // phase 3: convert prefetched x, write to next buffer
    if (it < 7) {
      u16* xb = smem + (cur ^ 1) * 8192;
#pragma unroll
      for (int q = 0; q < 4; ++q) {
        uint2 p;
        p.x = pack2(xf[q].x, xf[q].y);
        p.y = pack2(xf[q].z, xf[q].w);
        *(uint2*)&xb[xso[q]] = p;
      }
    }
    __syncthreads();
    cur ^= 1;
  }

  // ---- epilogue: itv -> LDS (bf16) + rotated chunk-total reduce
  float* totr = (float*)smem;          // [4][128]  bytes 0..2048
  float* toti = (float*)smem + 512;    // bytes 2048..4096
  u16* litv = smem + 8192;             // [128 t][128 k] u16, bytes 16384..49152

  float dtv[2][4], ctv[2][4];
#pragma unroll
  for (int m = 0; m < 2; ++m)
#pragma unroll
    for (int r = 0; r < 4; ++r) {
      int t = t0 + tw * 32 + m * 16 + lg * 4 + r;
      dtv[m][r] = dt[(size_t)b * TT + t];
      ctv[m][r] = ct[(size_t)b * TT + t];
    }

#pragma unroll
  for (int n = 0; n < 4; ++n) {
    int k = kw * 64 + n * 16 + lm;
    float pal = params[k], pom = params[KK + k];
    float pc1 = params[2 * KK + k], pc2 = params[3 * KK + k];
    float sr = 0.f, si2 = 0.f;
#pragma unroll
    for (int m = 0; m < 2; ++m)
#pragma unroll
      for (int r = 0; r < 4; ++r) {
        float g = acc[m][n][r];
        float a = pal * dtv[m][r];
        float omr = a * (1.f - a * (0.5f - a * (1.f / 6.f)));  // 1 - exp(-a)
        float itv = omr * (pc1 * g + pc2);
        int tl = tw * 32 + m * 16 + lg * 4 + r;
        litv[tl * KK + k] = (u16)cvt_bf16_rn(itv);
        float e = __expf(pal * ctv[m][r]);
        float sn, cs;
        __sincosf(pom * ctv[m][r], &sn, &cs);
        sr += itv * e * cs;
        si2 -= itv * e * sn;
      }
    sr += __shfl_xor(sr, 16, 64);
    sr += __shfl_xor(sr, 32, 64);
    si2 += __shfl_xor(si2, 16, 64);
    si2 += __shfl_xor(si2, 32, 64);
    if (lg == 0) { totr[tw * KK + k] = sr; toti[tw * KK + k] = si2; }
  }
  __syncthreads();

  // chunk totals (plain stores; dispatch boundary syncs with kernel B)
  if (tid < 256) {
    int v = tid & 127;
    float* src = (tid < 128) ? totr : toti;
    float* dst = (tid < 128) ? csum_re : csum_im;
    dst[((size_t)b * NCB + chunk) * KK + v] =
        (src[v] + src[KK + v]) + (src[2 * KK + v] + src[3 * KK + v]);
  }
  // itv coalesced store: 16 threads x 16B per row, 32 rows per round, 4 rounds
  {
    int row = tid >> 4;          // 0..31
    int c8 = (tid & 15) * 8;     // u16 offset
#pragma unroll
    for (int rr = 0; rr < 4; ++rr) {
      int tr = rr * 32 + row;
      uint4 v = *(const uint4*)&litv[tr * KK + c8];
      *(uint4*)&itvb[((size_t)b * TT + t0 + tr) * KK + c8] = v;
    }
  }
}

// ---------------- kernel B: prefix + single-trig scan + algebraic rotate ----------------
__global__ __launch_bounds__(512) void k_final(
    const u16* __restrict__ itvb, const float* __restrict__ ct,
    const float* __restrict__ params,
    const float* __restrict__ csum_re, const float* __restrict__ csum_im,
    float* __restrict__ out) {
  __shared__ float prer[KK], prei[KK];
  __shared__ float segr[16][KK], segi[16][KK];
  const int chunk = blockIdx.x, b = blockIdx.y;
  const int tid = threadIdx.x;
  const int k4 = (tid & 31) * 4, tseg = tid >> 5;   // 16 segments x 8 t
  const int tbase = chunk * TCB + tseg * 8;

  if (tid < 256) {
    int v = tid & 127;
    const float* srcp = (tid < 128) ? csum_re : csum_im;
    float* dstp = (tid < 128) ? prer : prei;
    size_t base = (size_t)b * NCB * KK + v;
    float a0 = 0.f, a1 = 0.f, a2 = 0.f, a3 = 0.f;
    int c = 0;
    for (; c + 4 <= chunk; c += 4) {
      a0 += srcp[base + (size_t)(c + 0) * KK];
      a1 += srcp[base + (size_t)(c + 1) * KK];
      a2 += srcp[base + (size_t)(c + 2) * KK];
      a3 += srcp[base + (size_t)(c + 3) * KK];
    }
    for (; c < chunk; ++c) a0 += srcp[base + (size_t)c * KK];
    dstp[v] = (a0 + a1) + (a2 + a3);
  }

  float4 pal4 = *(const float4*)&params[k4];
  float4 pom4 = *(const float4*)&params[KK + k4];
  float pal[4] = {pal4.x, pal4.y, pal4.z, pal4.w};
  float pom[4] = {pom4.x, pom4.y, pom4.z, pom4.w};

  uint2 iv8[8];
  float fr[8][4], fi[8][4];
  float sr[4] = {0.f, 0.f, 0.f, 0.f}, si[4] = {0.f, 0.f, 0.f, 0.f};
#pragma unroll
  for (int i = 0; i < 8; ++i) {
    int t = tbase + i;
    float ctv = ct[(size_t)b * TT + t];
    iv8[i] = *(const uint2*)&itvb[((size_t)b * TT + t) * KK + k4];
    float it[4] = {__uint_as_float(iv8[i].x << 16), __uint_as_float(iv8[i].x & 0xFFFF0000u),
                   __uint_as_float(iv8[i].y << 16), __uint_as_float(iv8[i].y & 0xFFFF0000u)};
#pragma unroll
    for (int c = 0; c < 4; ++c) {
      float e = __expf(pal[c] * ctv);
      float sn, cs;
      __sincosf(pom[c] * ctv, &sn, &cs);
      fr[i][c] = e * cs;
      fi[i][c] = e * sn;
      sr[c] += it[c] * fr[i][c];
      si[c] -= it[c] * fi[i][c];
    }
  }
  *(float4*)&segr[tseg][k4] = make_float4(sr[0], sr[1], sr[2], sr[3]);
  *(float4*)&segi[tseg][k4] = make_float4(si[0], si[1], si[2], si[3]);
  __syncthreads();
  float cr[4], ci[4];
  {
    float4 p0 = *(const float4*)&prer[k4];
    float4 p1 = *(const float4*)&prei[k4];
    cr[0] = p0.x; cr[1] = p0.y; cr[2] = p0.z; cr[3] = p0.w;
    ci[0] = p1.x; ci[1] = p1.y; ci[2] = p1.z; ci[3] = p1.w;
  }
  for (int s = 0; s < tseg; ++s) {
    float4 a = *(const float4*)&segr[s][k4];
    float4 bb = *(const float4*)&segi[s][k4];
    cr[0] += a.x; cr[1] += a.y; cr[2] += a.z; cr[3] += a.w;
    ci[0] += bb.x; ci[1] += bb.y; ci[2] += bb.z; ci[3] += bb.w;
  }
#pragma unroll
  for (int i = 0; i < 8; ++i) {
    int t = tbase + i;
    float it[4] = {__uint_as_float(iv8[i].x << 16), __uint_as_float(iv8[i].x & 0xFFFF0000u),
                   __uint_as_float(iv8[i].y << 16), __uint_as_float(iv8[i].y & 0xFFFF0000u)};
    float C4[4], S4[4];
#pragma unroll
    for (int c = 0; c < 4; ++c) {
      float f_r = fr[i][c], f_i = fi[i][c];
      cr[c] += it[c] * f_r;
      ci[c] -= it[c] * f_i;
      float inv = __builtin_amdgcn_rcpf(f_r * f_r + f_i * f_i);   // 1/e^2
      float Rw = (cr[c] * f_r - ci[c] * f_i) * inv;
      float Iw = (cr[c] * f_i + ci[c] * f_r) * inv;
      C4[c] = Rw - Iw;
      S4[c] = Rw + Iw;
    }
    size_t rowb = ((size_t)b * TT + t) * (2 * KK);
    *(float4*)&out[rowb + k4] = make_float4(C4[0], C4[1], C4[2], C4[3]);
    *(float4*)&out[rowb + KK + k4] = make_float4(S4[0], S4[1], S4[2], S4[3]);
  }
}

extern "C" void kernel_launch(void* const* d_in, const int* in_sizes, int n_in,
                              void* d_out, int out_size, void* d_ws, size_t ws_size,
                              hipStream_t stream) {
  const float* x    = (const float*)d_in[0];
  const float* dt   = (const float*)d_in[1];
  const float* srr  = (const float*)d_in[2];
  const float* si   = (const float*)d_in[3];
  const float* W    = (const float*)d_in[4];
  const float* bias = (const float*)d_in[5];
  const float* blog = (const float*)d_in[6];
  const float* usn  = (const float*)d_in[7];
  float* out = (float*)d_out;
  float* ws = (float*)d_ws;

  float* params  = ws;                          // 512 f
  float* ct      = ws + 4 * KK;                 // 65536 f
  float* csum_re = ct + (size_t)BB * TT;        // 65536 f
  float* csum_im = csum_re + (size_t)BB * NCB * KK;  // 65536 f
  u16*   Wp      = (u16*)(csum_im + (size_t)BB * NCB * KK);  // 65536 u16
  u16*   itvb    = Wp + 65536;                  // B*T*K u16 = 16 MB

  k_prep<<<81, 256, 0, stream>>>(W, usn, srr, si, bias, blog, dt, params, Wp, ct);
  k_gemm<<<dim3(NCB, BB), 512, 0, stream>>>(x, Wp, dt, ct, params, itvb,
                                            csum_re, csum_im);
  k_final<<<dim3(NCB, BB), 512, 0, stream>>>(itvb, ct, params,
                                             csum_re, csum_im, out);
}